// Round 8
// baseline (123.291 us; speedup 1.0000x reference)
//
#include <hip/hip_runtime.h>

#define L 2048
#define BS 4
#define CIN 32
#define COUT 32
#define HIDN 64
#define KK 8
#define TB 16
#define NBLK ((BS*L)/TB)      // 512 blocks = 256 CUs x 2 (one resident generation)
#define EPSV 1e-5f
#define QSTR (HIDN*CIN + 8)   // 2056 f16 row (+16B pad)

typedef _Float16 f16;
typedef _Float16 f16x2 __attribute__((ext_vector_type(2)));
typedef _Float16 f16x8 __attribute__((ext_vector_type(8)));
typedef __fp16   h16x2 __attribute__((ext_vector_type(2)));
typedef float    f32x2 __attribute__((ext_vector_type(2)));
typedef float    f32x4 __attribute__((ext_vector_type(4)));

// blocks 0..127: W2 -> MFMA B-fragments (f16). block 0 zeroes the 8 LN shards.
// block 128: W1 -> per-column f16 pairs.
__global__ __launch_bounds__(64) void prep(const float* __restrict__ W2,
                                           const float* __restrict__ W1,
                                           f16* __restrict__ w2h,
                                           f16* __restrict__ w1p,
                                           float* __restrict__ sums) {
    const int f    = blockIdx.x;
    const int lane = threadIdx.x;
    if (f == 128) {
        #pragma unroll
        for (int i2 = 0; i2 < 16; i2++) {
            w1p[lane*32 + i2*2 + 0] = (f16)W1[(2*i2 + 0)*HIDN + lane];
            w1p[lane*32 + i2*2 + 1] = (f16)W1[(2*i2 + 1)*HIDN + lane];
        }
        return;
    }
    if (f == 0) {
        #pragma unroll
        for (int j = 0; j < 8; j++) sums[j*64 + lane] = 0.f;
    }
    const int kb = f >> 1, nt = f & 1;
    const int m = lane & 15, qd = lane >> 4;
    #pragma unroll
    for (int j = 0; j < 8; j++)
        w2h[(f*64 + lane)*8 + j] = (f16)W2[(kb*32 + qd*8 + j)*32 + nt*16 + m];
}

__global__ __launch_bounds__(512, 4) void cc_main(
    const float* __restrict__ times,
    const float* __restrict__ features,
    const int*   __restrict__ mask,
    const float* __restrict__ b1,
    const float* __restrict__ b2,
    const float* __restrict__ Wsk,
    const float* __restrict__ bsk,
    const f16*   __restrict__ w2h,
    const f16*   __restrict__ w1p,
    float* __restrict__ out,
    float* __restrict__ sums)        // 8 shards x 64
{
    // LDS: 65792 (s_Q; aliases s_te/s_f in phase A, s_part in tail)
    //      + 2048 + 2048 = 69888 B -> 2 blocks/CU, 16 waves/CU
    __shared__ __align__(16) char s_pool[TB * QSTR * 2];
    f16   (*s_Q )[QSTR]      = (f16  (*)[QSTR])    s_pool;
    f16   (*s_te)[KK][CIN]   = (f16  (*)[KK][CIN]) s_pool;          // 8 KB alias
    float (*s_f )[KK][CIN]   = (float(*)[KK][CIN])(s_pool + 8192);  // 16 KB alias
    float (*s_part)[TB][COUT]= (float(*)[TB][COUT])s_pool;          // 16 KB alias (tail)
    __shared__ float s_F [TB][CIN];
    __shared__ float s_ft[TB][CIN];

    const int tid = threadIdx.x;
    const int tl  = tid >> 5;        // 0..15
    const int x   = tid & 31;
    const int bt  = blockIdx.x * TB + tl;
    const int b   = bt >> 11;
    const int t   = bt & (L - 1);

    // ---- hoisted weight loads (overlap stage-1 latency) ----
    union UH { f16x8 v8[4]; f16x2 d2[16]; } wa, wb;
    #pragma unroll
    for (int i = 0; i < 4; i++) {
        wa.v8[i] = ((const f16x8*)(w1p + x*32))[i];
        wb.v8[i] = ((const f16x8*)(w1p + (x + 32)*32))[i];
    }
    const float b1a = b1[x], b1b = b1[x + 32];

    // ---- stage 1: all loads unconditional & independent ----
    const float t_cur = times[b*L + t];
    const int   np_t  = mask[b*L + t];
    float tv[KK], fr[KK];
    int   mv[KK];
    #pragma unroll
    for (int k = 0; k < KK; k++) {
        const int idx  = t - (KK - 1) + k;
        const int idxc = idx > 0 ? idx : 0;
        tv[k] = times[b*L + idxc];
        mv[k] = mask[b*L + idxc];
        fr[k] = features[(b*L + idxc)*CIN + x];
    }
    const float inv_pos = exp2f(-(float)(x >> 1) * (13.2877123795f / 16.0f));
    float Fx = 0.f;
    #pragma unroll
    for (int k = 0; k < KK; k++) {
        const int dm  = (t - (KK - 1) + k >= 0) && np_t && mv[k];
        const float r = (t_cur - tv[k]) * inv_pos;
        s_te[tl][k][x] = (f16)((x & 1) ? __cosf(r) : __sinf(r));
        const float fv = dm ? fr[k] : 0.f;            // all masking folds into f
        s_f[tl][k][x] = fv;
        Fx += fv;
    }
    s_F [tl][x] = Fx;
    s_ft[tl][x] = features[(b*L + t)*CIN + x];
    __syncthreads();                                  // B1

    // ---- phase A: rank-8 Q build; 4 independent fdot2 chains ----
    f32x2 q0[16], q1[16];
    #pragma unroll
    for (int c = 0; c < 16; c++) { q0[c] = (f32x2){0.f,0.f}; q1[c] = (f32x2){0.f,0.f}; }

    #pragma unroll
    for (int k = 0; k < KK; k++) {
        union UT { f16x8 v8[4]; f16x2 d2[16]; } te;
        union UF { f32x4 v4[8]; f32x2 d2[16]; } ff;
        #pragma unroll
        for (int i = 0; i < 4; i++) te.v8[i] = ((const f16x8*)&s_te[tl][k][0])[i];
        #pragma unroll
        for (int i = 0; i < 8; i++) ff.v4[i] = ((const f32x4*)&s_f[tl][k][0])[i];

        float a0 = 0.f, a1 = 0.f, a2 = 0.f, a3 = 0.f;
        float c0 = 0.f, c1 = 0.f, c2 = 0.f, c3 = 0.f;
        #pragma unroll
        for (int g = 0; g < 4; g++) {
            a0 = __builtin_amdgcn_fdot2(te.d2[g*4+0], wa.d2[g*4+0], a0, false);
            a1 = __builtin_amdgcn_fdot2(te.d2[g*4+1], wa.d2[g*4+1], a1, false);
            a2 = __builtin_amdgcn_fdot2(te.d2[g*4+2], wa.d2[g*4+2], a2, false);
            a3 = __builtin_amdgcn_fdot2(te.d2[g*4+3], wa.d2[g*4+3], a3, false);
            c0 = __builtin_amdgcn_fdot2(te.d2[g*4+0], wb.d2[g*4+0], c0, false);
            c1 = __builtin_amdgcn_fdot2(te.d2[g*4+1], wb.d2[g*4+1], c1, false);
            c2 = __builtin_amdgcn_fdot2(te.d2[g*4+2], wb.d2[g*4+2], c2, false);
            c3 = __builtin_amdgcn_fdot2(te.d2[g*4+3], wb.d2[g*4+3], c3, false);
        }
        const float ha = fmaxf(((a0 + a1) + (a2 + a3)) + b1a, 0.f);
        const float hb = fmaxf(((c0 + c1) + (c2 + c3)) + b1b, 0.f);
        const f32x2 h2a = {ha, ha}, h2b = {hb, hb};
        #pragma unroll
        for (int c = 0; c < 16; c++) {
            q0[c] = h2a * ff.d2[c] + q0[c];
            q1[c] = h2b * ff.d2[c] + q1[c];
        }
    }
    __syncthreads();                                  // B2 (te/f dead, s_Q alias safe)

    // ---- pack Q to f16 LDS, XOR-swizzled: ch = (h*4+cj)^(h&7) ----
    const int sw = x & 7;
    #pragma unroll
    for (int cj = 0; cj < 4; cj++) {
        union { f16x8 v8; h16x2 v2[4]; } p0, p1;
        #pragma unroll
        for (int j = 0; j < 4; j++) {
            p0.v2[j] = __builtin_amdgcn_cvt_pkrtz(q0[cj*4 + j][0], q0[cj*4 + j][1]);
            p1.v2[j] = __builtin_amdgcn_cvt_pkrtz(q1[cj*4 + j][0], q1[cj*4 + j][1]);
        }
        const int ch0 = ((x*4 + cj) ^ sw);
        const int ch1 = (((x + 32)*4 + cj) ^ sw);
        *(f16x8*)&s_Q[tl][ch0*8] = p0.v8;
        *(f16x8*)&s_Q[tl][ch1*8] = p1.v8;
    }

    // extras: b_skip + feat@Wsk + F@b2rows (overlaps the barrier)
    float ex = bsk[x];
    #pragma unroll
    for (int c = 0; c < CIN; c++) ex = fmaf(s_ft[tl][c], Wsk[c*COUT + x], ex);
    #pragma unroll
    for (int c = 0; c < CIN; c++) ex = fmaf(s_F [tl][c], b2 [c*COUT + x], ex);
    __syncthreads();                                  // B3 (publish s_Q)

    // ---- phase B: MFMA, 16 real rows, K=2048 split over 8 waves ----
    {
        const int wv   = tid >> 6;                    // 0..7
        const int lane = tid & 63;
        const int m    = lane & 15, qd = lane >> 4;
        f32x4 C0 = {0.f,0.f,0.f,0.f}, C1 = {0.f,0.f,0.f,0.f};
        #pragma unroll
        for (int kb = wv*8; kb < wv*8 + 8; kb++) {
            const int ch = ((kb*4 + qd) ^ (kb & 7));
            const f16x8 a   = *(const f16x8*)&s_Q[m][ch*8];
            const f16x8 bf0 = ((const f16x8*)w2h)[(kb*2 + 0)*64 + lane];
            const f16x8 bf1 = ((const f16x8*)w2h)[(kb*2 + 1)*64 + lane];
            C0 = __builtin_amdgcn_mfma_f32_16x16x32_f16(a, bf0, C0, 0, 0, 0);
            C1 = __builtin_amdgcn_mfma_f32_16x16x32_f16(a, bf1, C1, 0, 0, 0);
        }
        __syncthreads();                              // B4a: all s_Q reads done
        #pragma unroll
        for (int r = 0; r < 4; r++) {                 // D: col=lane&15, row=qd*4+r
            s_part[wv][qd*4 + r][m]      = C0[r];
            s_part[wv][qd*4 + r][16 + m] = C1[r];
        }
    }
    __syncthreads();                                  // B4b

    float val = ex;
    #pragma unroll
    for (int w = 0; w < 8; w++) val += s_part[w][tl][x];
    out[(b*L + t)*COUT + x] = val;

    s_F [tl][x] = val;
    s_ft[tl][x] = val * val;
    __syncthreads();                                  // B5
    if (tid < 32) {
        float s1 = 0.f, s2 = 0.f;
        #pragma unroll
        for (int j = 0; j < TB; j++) { s1 += s_F[j][x]; s2 += s_ft[j][x]; }
        float* shard = sums + (blockIdx.x & 7) * 64;
        atomicAdd(&shard[x],      s1);
        atomicAdd(&shard[32 + x], s2);
    }
}

__global__ __launch_bounds__(256) void cc_norm(
    float4* __restrict__ out, const float* __restrict__ sums,
    const float* __restrict__ gamma, const float* __restrict__ beta)
{
    const int i  = blockIdx.x * 256 + threadIdx.x;    // float4 index
    const int o0 = (i & 7) * 4;
    const float n = (float)(BS * L);
    float4 v = out[i], r;
    float* vp = &v.x; float* rp = &r.x;
    #pragma unroll
    for (int j = 0; j < 4; j++) {
        const int o = o0 + j;
        float s1 = 0.f, s2 = 0.f;
        #pragma unroll
        for (int s = 0; s < 8; s++) { s1 += sums[s*64 + o]; s2 += sums[s*64 + 32 + o]; }
        const float mean = s1 / n;
        const float var  = s2 / n - mean * mean;
        rp[j] = gamma[o] * (vp[j] - mean) * rsqrtf(var + EPSV) + beta[o];
    }
    out[i] = r;
}

extern "C" void kernel_launch(void* const* d_in, const int* in_sizes, int n_in,
                              void* d_out, int out_size, void* d_ws, size_t ws_size,
                              hipStream_t stream) {
    const float* times    = (const float*)d_in[0];
    const float* features = (const float*)d_in[1];
    const int*   mask     = (const int*)  d_in[2];
    const float* W1       = (const float*)d_in[3];
    const float* b1       = (const float*)d_in[4];
    const float* W2       = (const float*)d_in[5];
    const float* b2       = (const float*)d_in[6];
    const float* Wsk      = (const float*)d_in[7];
    const float* bsk      = (const float*)d_in[8];
    const float* gamma    = (const float*)d_in[9];
    const float* beta     = (const float*)d_in[10];
    float* out  = (float*)d_out;
    float* sums = (float*)d_ws;                          // 512 floats (8 shards)
    f16*   w2h  = (f16*)((char*)d_ws + 4096);            // 128 KB
    f16*   w1p  = (f16*)((char*)d_ws + 4096 + 131072);   // 4 KB

    prep<<<129, 64, 0, stream>>>(W2, W1, w2h, w1p, sums);
    cc_main<<<NBLK, 512, 0, stream>>>(times, features, mask, b1,
                                      b2, Wsk, bsk, w2h, w1p, out, sums);
    cc_norm<<<(BS*L*COUT)/(4*256), 256, 0, stream>>>((float4*)out, sums, gamma, beta);
}

// Round 9
// 95.463 us; speedup vs baseline: 1.2915x; 1.2915x over previous
//
#include <hip/hip_runtime.h>

#define L 2048
#define BS 4
#define CIN 32
#define COUT 32
#define HIDN 64
#define KK 8
#define TB 16
#define NBLK ((BS*L)/TB)      // 512 blocks = 256 CUs x 2 (one resident generation)
#define EPSV 1e-5f
#define QSTR (HIDN*CIN + 8)   // 2056 f16 row (+16B pad)

typedef _Float16 f16;
typedef _Float16 f16x2 __attribute__((ext_vector_type(2)));
typedef _Float16 f16x8 __attribute__((ext_vector_type(8)));
typedef __fp16   h16x2 __attribute__((ext_vector_type(2)));
typedef float    f32x2 __attribute__((ext_vector_type(2)));
typedef float    f32x4 __attribute__((ext_vector_type(4)));

// blocks 0..127: W2 -> MFMA B-fragments (f16). block 0 zeroes the 8 LN shards.
// block 128: W1 -> per-column f16 pairs.
__global__ __launch_bounds__(64) void prep(const float* __restrict__ W2,
                                           const float* __restrict__ W1,
                                           f16* __restrict__ w2h,
                                           f16* __restrict__ w1p,
                                           float* __restrict__ sums) {
    const int f    = blockIdx.x;
    const int lane = threadIdx.x;
    if (f == 128) {
        #pragma unroll
        for (int i2 = 0; i2 < 16; i2++) {
            w1p[lane*32 + i2*2 + 0] = (f16)W1[(2*i2 + 0)*HIDN + lane];
            w1p[lane*32 + i2*2 + 1] = (f16)W1[(2*i2 + 1)*HIDN + lane];
        }
        return;
    }
    if (f == 0) {
        #pragma unroll
        for (int j = 0; j < 8; j++) sums[j*64 + lane] = 0.f;
    }
    const int kb = f >> 1, nt = f & 1;
    const int m = lane & 15, qd = lane >> 4;
    #pragma unroll
    for (int j = 0; j < 8; j++)
        w2h[(f*64 + lane)*8 + j] = (f16)W2[(kb*32 + qd*8 + j)*32 + nt*16 + m];
}

// launch_bounds(512,2): 256-VGPR budget. (512,4) empirically caps at 64 VGPR
// -> 84 MB of spill traffic (R8). Occupancy is LDS-bound (70 KB -> 2 blk/CU).
__global__ __launch_bounds__(512, 2) void cc_main(
    const float* __restrict__ times,
    const float* __restrict__ features,
    const int*   __restrict__ mask,
    const float* __restrict__ b1,
    const float* __restrict__ b2,
    const float* __restrict__ Wsk,
    const float* __restrict__ bsk,
    const f16*   __restrict__ w2h,
    const f16*   __restrict__ w1p,
    float* __restrict__ out,
    float* __restrict__ sums)        // 8 shards x 64
{
    // LDS: 65792 (s_Q; aliases s_te/s_f in phase A, s_part in tail)
    //      + 2048 + 2048 = 69888 B -> 2 blocks/CU, 16 waves/CU
    __shared__ __align__(16) char s_pool[TB * QSTR * 2];
    f16   (*s_Q )[QSTR]      = (f16  (*)[QSTR])    s_pool;
    f16   (*s_te)[KK][CIN]   = (f16  (*)[KK][CIN]) s_pool;          // 8 KB alias
    float (*s_f )[KK][CIN]   = (float(*)[KK][CIN])(s_pool + 8192);  // 16 KB alias
    float (*s_part)[TB][COUT]= (float(*)[TB][COUT])s_pool;          // 16 KB alias (tail)
    __shared__ float s_F [TB][CIN];
    __shared__ float s_ft[TB][CIN];

    const int tid = threadIdx.x;
    const int tl  = tid >> 5;        // 0..15
    const int x   = tid & 31;
    const int bt  = blockIdx.x * TB + tl;
    const int b   = bt >> 11;
    const int t   = bt & (L - 1);

    // ---- hoisted weight loads (overlap stage-1 latency) ----
    union UH { f16x8 v8[4]; f16x2 d2[16]; } wa, wb;
    #pragma unroll
    for (int i = 0; i < 4; i++) {
        wa.v8[i] = ((const f16x8*)(w1p + x*32))[i];
        wb.v8[i] = ((const f16x8*)(w1p + (x + 32)*32))[i];
    }
    const float b1a = b1[x], b1b = b1[x + 32];

    // ---- stage 1: all loads unconditional & independent ----
    const float t_cur = times[b*L + t];
    const int   np_t  = mask[b*L + t];
    float tv[KK], fr[KK];
    int   mv[KK];
    #pragma unroll
    for (int k = 0; k < KK; k++) {
        const int idx  = t - (KK - 1) + k;
        const int idxc = idx > 0 ? idx : 0;
        tv[k] = times[b*L + idxc];
        mv[k] = mask[b*L + idxc];
        fr[k] = features[(b*L + idxc)*CIN + x];
    }
    const float inv_pos = exp2f(-(float)(x >> 1) * (13.2877123795f / 16.0f));
    float Fx = 0.f;
    #pragma unroll
    for (int k = 0; k < KK; k++) {
        const int dm  = (t - (KK - 1) + k >= 0) && np_t && mv[k];
        const float r = (t_cur - tv[k]) * inv_pos;
        s_te[tl][k][x] = (f16)((x & 1) ? __cosf(r) : __sinf(r));
        const float fv = dm ? fr[k] : 0.f;            // all masking folds into f
        s_f[tl][k][x] = fv;
        Fx += fv;
    }
    s_F [tl][x] = Fx;
    s_ft[tl][x] = features[(b*L + t)*CIN + x];
    __syncthreads();                                  // B1

    // ---- phase A: rank-8 Q build; 4 independent fdot2 chains ----
    f32x2 q0[16], q1[16];
    #pragma unroll
    for (int c = 0; c < 16; c++) { q0[c] = (f32x2){0.f,0.f}; q1[c] = (f32x2){0.f,0.f}; }

    for (int k = 0; k < KK; k++) {                    // no unroll: keep VGPR pressure low
        union UT { f16x8 v8[4]; f16x2 d2[16]; } te;
        union UF { f32x4 v4[8]; f32x2 d2[16]; } ff;
        #pragma unroll
        for (int i = 0; i < 4; i++) te.v8[i] = ((const f16x8*)&s_te[tl][k][0])[i];
        #pragma unroll
        for (int i = 0; i < 8; i++) ff.v4[i] = ((const f32x4*)&s_f[tl][k][0])[i];

        float a0 = 0.f, a1 = 0.f, a2 = 0.f, a3 = 0.f;
        float c0 = 0.f, c1 = 0.f, c2 = 0.f, c3 = 0.f;
        #pragma unroll
        for (int g = 0; g < 4; g++) {
            a0 = __builtin_amdgcn_fdot2(te.d2[g*4+0], wa.d2[g*4+0], a0, false);
            a1 = __builtin_amdgcn_fdot2(te.d2[g*4+1], wa.d2[g*4+1], a1, false);
            a2 = __builtin_amdgcn_fdot2(te.d2[g*4+2], wa.d2[g*4+2], a2, false);
            a3 = __builtin_amdgcn_fdot2(te.d2[g*4+3], wa.d2[g*4+3], a3, false);
            c0 = __builtin_amdgcn_fdot2(te.d2[g*4+0], wb.d2[g*4+0], c0, false);
            c1 = __builtin_amdgcn_fdot2(te.d2[g*4+1], wb.d2[g*4+1], c1, false);
            c2 = __builtin_amdgcn_fdot2(te.d2[g*4+2], wb.d2[g*4+2], c2, false);
            c3 = __builtin_amdgcn_fdot2(te.d2[g*4+3], wb.d2[g*4+3], c3, false);
        }
        const float ha = fmaxf(((a0 + a1) + (a2 + a3)) + b1a, 0.f);
        const float hb = fmaxf(((c0 + c1) + (c2 + c3)) + b1b, 0.f);
        const f32x2 h2a = {ha, ha}, h2b = {hb, hb};
        #pragma unroll
        for (int c = 0; c < 16; c++) {
            q0[c] = h2a * ff.d2[c] + q0[c];
            q1[c] = h2b * ff.d2[c] + q1[c];
        }
    }
    __syncthreads();                                  // B2 (te/f dead, s_Q alias safe)

    // ---- pack Q to f16 LDS, XOR-swizzled: ch = (h*4+cj)^(h&7) ----
    const int sw = x & 7;
    #pragma unroll
    for (int cj = 0; cj < 4; cj++) {
        union { f16x8 v8; h16x2 v2[4]; } p0, p1;
        #pragma unroll
        for (int j = 0; j < 4; j++) {
            p0.v2[j] = __builtin_amdgcn_cvt_pkrtz(q0[cj*4 + j][0], q0[cj*4 + j][1]);
            p1.v2[j] = __builtin_amdgcn_cvt_pkrtz(q1[cj*4 + j][0], q1[cj*4 + j][1]);
        }
        const int ch0 = ((x*4 + cj) ^ sw);
        const int ch1 = (((x + 32)*4 + cj) ^ sw);
        *(f16x8*)&s_Q[tl][ch0*8] = p0.v8;
        *(f16x8*)&s_Q[tl][ch1*8] = p1.v8;
    }

    // extras: b_skip + feat@Wsk + F@b2rows (overlaps the barrier)
    float ex = bsk[x];
    #pragma unroll
    for (int c = 0; c < CIN; c++) ex = fmaf(s_ft[tl][c], Wsk[c*COUT + x], ex);
    #pragma unroll
    for (int c = 0; c < CIN; c++) ex = fmaf(s_F [tl][c], b2 [c*COUT + x], ex);
    __syncthreads();                                  // B3 (publish s_Q)

    // ---- phase B: MFMA, 16 real rows, K=2048 split over 8 waves ----
    {
        const int wv   = tid >> 6;                    // 0..7
        const int lane = tid & 63;
        const int m    = lane & 15, qd = lane >> 4;
        f32x4 C0 = {0.f,0.f,0.f,0.f}, C1 = {0.f,0.f,0.f,0.f};
        #pragma unroll
        for (int kb = wv*8; kb < wv*8 + 8; kb++) {
            const int ch = ((kb*4 + qd) ^ (kb & 7));
            const f16x8 a   = *(const f16x8*)&s_Q[m][ch*8];
            const f16x8 bf0 = ((const f16x8*)w2h)[(kb*2 + 0)*64 + lane];
            const f16x8 bf1 = ((const f16x8*)w2h)[(kb*2 + 1)*64 + lane];
            C0 = __builtin_amdgcn_mfma_f32_16x16x32_f16(a, bf0, C0, 0, 0, 0);
            C1 = __builtin_amdgcn_mfma_f32_16x16x32_f16(a, bf1, C1, 0, 0, 0);
        }
        __syncthreads();                              // B4a: all s_Q reads done
        #pragma unroll
        for (int r = 0; r < 4; r++) {                 // D: col=lane&15, row=qd*4+r
            s_part[wv][qd*4 + r][m]      = C0[r];
            s_part[wv][qd*4 + r][16 + m] = C1[r];
        }
    }
    __syncthreads();                                  // B4b

    float val = ex;
    #pragma unroll
    for (int w = 0; w < 8; w++) val += s_part[w][tl][x];
    out[(b*L + t)*COUT + x] = val;

    s_F [tl][x] = val;
    s_ft[tl][x] = val * val;
    __syncthreads();                                  // B5
    if (tid < 32) {
        float s1 = 0.f, s2 = 0.f;
        #pragma unroll
        for (int j = 0; j < TB; j++) { s1 += s_F[j][x]; s2 += s_ft[j][x]; }
        float* shard = sums + (blockIdx.x & 7) * 64;
        atomicAdd(&shard[x],      s1);
        atomicAdd(&shard[32 + x], s2);
    }
}

__global__ __launch_bounds__(256) void cc_norm(
    float4* __restrict__ out, const float* __restrict__ sums,
    const float* __restrict__ gamma, const float* __restrict__ beta)
{
    const int i  = blockIdx.x * 256 + threadIdx.x;    // float4 index
    const int o0 = (i & 7) * 4;
    const float n = (float)(BS * L);
    float4 v = out[i], r;
    float* vp = &v.x; float* rp = &r.x;
    #pragma unroll
    for (int j = 0; j < 4; j++) {
        const int o = o0 + j;
        float s1 = 0.f, s2 = 0.f;
        #pragma unroll
        for (int s = 0; s < 8; s++) { s1 += sums[s*64 + o]; s2 += sums[s*64 + 32 + o]; }
        const float mean = s1 / n;
        const float var  = s2 / n - mean * mean;
        rp[j] = gamma[o] * (vp[j] - mean) * rsqrtf(var + EPSV) + beta[o];
    }
    out[i] = r;
}

extern "C" void kernel_launch(void* const* d_in, const int* in_sizes, int n_in,
                              void* d_out, int out_size, void* d_ws, size_t ws_size,
                              hipStream_t stream) {
    const float* times    = (const float*)d_in[0];
    const float* features = (const float*)d_in[1];
    const int*   mask     = (const int*)  d_in[2];
    const float* W1       = (const float*)d_in[3];
    const float* b1       = (const float*)d_in[4];
    const float* W2       = (const float*)d_in[5];
    const float* b2       = (const float*)d_in[6];
    const float* Wsk      = (const float*)d_in[7];
    const float* bsk      = (const float*)d_in[8];
    const float* gamma    = (const float*)d_in[9];
    const float* beta     = (const float*)d_in[10];
    float* out  = (float*)d_out;
    float* sums = (float*)d_ws;                          // 512 floats (8 shards)
    f16*   w2h  = (f16*)((char*)d_ws + 4096);            // 128 KB
    f16*   w1p  = (f16*)((char*)d_ws + 4096 + 131072);   // 4 KB

    prep<<<129, 64, 0, stream>>>(W2, W1, w2h, w1p, sums);
    cc_main<<<NBLK, 512, 0, stream>>>(times, features, mask, b1,
                                      b2, Wsk, bsk, w2h, w1p, out, sums);
    cc_norm<<<(BS*L*COUT)/(4*256), 256, 0, stream>>>((float4*)out, sums, gamma, beta);
}